// Round 4
// baseline (149.048 us; speedup 1.0000x reference)
//
#include <hip/hip_runtime.h>

// Balloon-Windkessel BOLD, explicit Euler, T=1000, B=16384.
// alpha==1 decouples the system: (s,f) is an affine scan with constant 2x2
// matrix A; v,q are affine scans with constant scalar av = 1-DT/lamb. Only
// E(f) is nonlinear (pointwise). Parallelize T:
//   40 chunks x 25 steps; block = 16 sims x 40 chunks = 640 threads.
//
// ROUND-4 INSIGHT: r0/r1/r3 all plateau at ~48us because pending global
// loads live in VGPRs -> ~8 in flight/wave x 20 waves/CU ~ 1.3 KB/CU
// outstanding, which caps fetch at ~1.7 TB/s (need ~6-9 KB/CU for 6.3).
// Fix: stage each block's whole noise slice (1000 x 16 sims = 64 KB) into
// LDS ONCE via __builtin_amdgcn_global_load_lds (DMA queue holds the
// in-flight bytes, zero VGPR cost, ~1KB per wave-instr). All phases then
// read z from LDS; P2 overwrites each dead z slot with its step's f so P3
// needs no (s,f) replay. HBM traffic = 64 MB read + 64 MB write (minimum).
//   stage: 62 x width-16 + 2 x width-4 DMA instrs, spread over 10 waves
//   P1: (s,f) chunk aggregate                    (z from LDS)
//   scan1 (LDS, Hillis-Steele, A^(25*2^j), 6 lvls) -> chunk-start (s,f)
//   P2: replay f, accumulate v,q aggregates; stash f into z slot
//   scan2 (scalar av^(25*2^j))                   -> chunk-start (v,q)
//   P3: consume stashed f, compute y, NT store
// LDS 69120 B/block -> 2 blocks/CU (20 waves/CU), grid 1024.
// Chunk-power matrices computed once in f64 keep chunk-start rounding
// ~1e-6; f stash is bit-identical to P3 replay (same ops, same start).

#define BATCH     16384
#define DT        0.01f
#define NOISE_AMP 0.01f
#define V0        0.02f
#define CHUNKS    40
#define CL        25          // 40 * 25 = 1000 steps
#define LANES     16          // lanes per chunk-row
#define GSIMS     16          // sims per block
#define NTHREADS  (CHUNKS * LANES)   // 640
#define LEVELS    6           // ceil(log2(40))
#define ZROWS     1000
#define ZTILE     (ZROWS * GSIMS)    // 16000 floats = 64000 B

#if __has_builtin(__builtin_amdgcn_exp2f)
#define EXP2F(x) __builtin_amdgcn_exp2f(x)
#else
#define EXP2F(x) exp2f(x)
#endif

#define AS1(p) ((__attribute__((address_space(1))) void*)(p))
#define AS3(p) ((__attribute__((address_space(3))) void*)(p))

__device__ __forceinline__ float uf(float x) {
    return __uint_as_float(__builtin_amdgcn_readfirstlane(__float_as_uint(x)));
}

struct D22 { double a, b, c, d; };
__device__ __forceinline__ D22 dmul(D22 x, D22 y) {
    D22 r;
    r.a = x.a * y.a + x.b * y.c;  r.b = x.a * y.b + x.b * y.d;
    r.c = x.c * y.a + x.d * y.c;  r.d = x.c * y.b + x.d * y.d;
    return r;
}

__global__ __launch_bounds__(NTHREADS, 5) void balloon_scan(
    const float* __restrict__ noise,
    const float* __restrict__ p_sigma,
    const float* __restrict__ p_mu,
    const float* __restrict__ p_lamb,
    const float* __restrict__ p_beta,
    const float* __restrict__ p_psi,
    const float* __restrict__ p_phi,
    const float* __restrict__ p_chi,
    float* __restrict__ out)
{
    const int tid = threadIdx.x;
    const int g   = tid & (LANES - 1);   // sim within block
    const int cc  = tid >> 4;            // chunk 0..39
    const int sim0 = blockIdx.x * GSIMS;
    const int sim  = sim0 + g;

    __shared__ float zt[ZTILE];
    __shared__ float sA[NTHREADS];
    __shared__ float sB[NTHREADS];

    // ---------------- stage: whole block slice -> LDS via DMA ----------------
    // LDS layout zt[t][s]: float idx t*16 + s. Width-16 instr i covers flat
    // bytes [i*1024, i*1024+1024): lane l -> t = 16i + l/4, s = (l&3)*4.
    // HW writes LDS at (uniform base) + lane*16.
    {
        const int wid  = tid >> 6;       // wave 0..9
        const int lane = tid & 63;
        for (int i = wid; i < 62; i += 10) {
            const int t = 16 * i + (lane >> 2);
            const int s = (lane & 3) * 4;
            const float* gp = noise + (size_t)t * BATCH + sim0 + s;
            __builtin_amdgcn_global_load_lds(AS1(gp), AS3(&zt[i * 256]), 16, 0, 0);
        }
        // tail rows 992..999: 2 width-4 instrs (64 lanes x 4 B = 4 rows each)
        if (wid < 2) {
            const int t = 992 + 4 * wid + (lane >> 4);
            const int s = lane & 15;
            const float* gp = noise + (size_t)t * BATCH + sim0 + s;
            __builtin_amdgcn_global_load_lds(AS1(gp), AS3(&zt[15872 + wid * 64]), 4, 0, 0);
        }
    }

    const float sigma = uf(p_sigma[0]);
    const float mu    = uf(p_mu[0]);
    const float lamb  = uf(p_lamb[0]);
    const float beta  = uf(p_beta[0]);
    const float psi   = uf(p_psi[0]);
    const float phi   = uf(p_phi[0]);
    const float chi   = uf(p_chi[0]);

    // ---- uniform fp32 step constants (identical forms to the validated R2) ----
    const float as_   = 1.0f - DT * sigma;
    const float dtn   = DT * NOISE_AMP;
    const float dtm   = DT * mu;
    const float dt_il = uf((float)(0.01 / (double)lamb));
    const float av    = 1.0f - dt_il;
    const float kq    = uf(dt_il / beta);
    const float lc    = uf(log2f(1.0f - beta));
    const float c0 = V0 * (phi + psi + chi), c1 = V0 * phi, c2 = V0 * psi, c3 = V0 * chi;

    // ---- chunk-power weights in f64, once: A^(25*2^j), av^(25*2^j) ----
    D22 A; A.a = 1.0 - 0.01 * (double)sigma; A.b = -0.01 * (double)mu;
           A.c = 0.01;                       A.d = 1.0;
    D22 A2 = dmul(A, A), A4 = dmul(A2, A2), A8 = dmul(A4, A4);
    D22 A16 = dmul(A8, A8);
    D22 P = dmul(dmul(A16, A8), A);                 // A^25
    double avd = 1.0 - 0.01 / (double)lamb;
    double av2 = avd * avd, av4 = av2 * av2, av8 = av4 * av4;
    double av16 = av8 * av8;
    double ap = av16 * av8 * avd;                   // av^25

    float M11[LEVELS], M12[LEVELS], M21[LEVELS], M22[LEVELS], AVP[LEVELS];
#pragma unroll
    for (int j = 0; j < LEVELS; ++j) {
        M11[j] = uf((float)P.a); M12[j] = uf((float)P.b);
        M21[j] = uf((float)P.c); M22[j] = uf((float)P.d);
        AVP[j] = uf((float)ap);
        P = dmul(P, P); ap = ap * ap;
    }

    // homogeneous parts at this thread's chunk start: A^(25c)*(0,1), av^(25c)*1
    float ws = 0.0f, wf = 1.0f, avc = 1.0f;
#pragma unroll
    for (int j = 0; j < LEVELS; ++j) {
        if ((cc >> j) & 1) {
            float t = __builtin_fmaf(M11[j], ws, M12[j] * wf);
            wf = __builtin_fmaf(M21[j], ws, M22[j] * wf);
            ws = t;
            avc *= AVP[j];
        }
    }

    // wait for the DMA stage (barrier drains vmcnt) before reading zt
    __syncthreads();

    const int zbase = (cc * CL) * GSIMS + g;

    // ---------------- P1: (s,f) chunk aggregate ----------------
    float rs = 0.0f, rf = 0.0f;
#pragma unroll 5
    for (int j = 0; j < CL; ++j) {
        const float z = zt[zbase + j * GSIMS];
        const float u = __builtin_fmaf(dtn, z, dtm);
        const float t = __builtin_fmaf(as_, rs, __builtin_fmaf(-dtm, rf, u));
        rf = __builtin_fmaf(DT, rs, rf);
        rs = t;
    }

    // ---------------- scan1: inclusive over chunks, matrix weights ----------------
    sA[tid] = rs; sB[tid] = rf;
    __syncthreads();
#pragma unroll
    for (int j = 0; j < LEVELS; ++j) {
        const int off = 1 << j;
        float ns = 0.0f, nf = 0.0f;
        const bool has = (cc >= off);
        if (has) { ns = sA[tid - off * LANES]; nf = sB[tid - off * LANES]; }
        __syncthreads();
        if (has) {
            rs = __builtin_fmaf(M11[j], ns, __builtin_fmaf(M12[j], nf, rs));
            rf = __builtin_fmaf(M21[j], ns, __builtin_fmaf(M22[j], nf, rf));
            sA[tid] = rs; sB[tid] = rf;
        }
        __syncthreads();
    }
    float s0 = ws, f0 = wf;
    if (cc > 0) { s0 += sA[tid - LANES]; f0 += sB[tid - LANES]; }
    __syncthreads();   // sA/sB reads done; safe to reuse for scan2

    // ---------------- P2: replay f, accumulate v,q aggregates; stash f ----------------
    float s = s0, f = f0, Rv = 0.0f, Rq = 0.0f;
#pragma unroll 5
    for (int j = 0; j < CL; ++j) {
        const int idx = zbase + j * GSIMS;
        const float z = zt[idx];
        const float invf = __builtin_amdgcn_rcpf(f);
        const float e2   = EXP2F(lc * invf);
        const float t1   = __builtin_fmaf(-f, e2, f);       // f*E(f)
        Rv = __builtin_fmaf(av, Rv, dt_il * f);
        Rq = __builtin_fmaf(av, Rq, kq * t1);
        zt[idx] = f;                                        // stash f_j for P3
        const float s2 = __builtin_fmaf(as_, s,
                         __builtin_fmaf(dtn, z,
                         __builtin_fmaf(-dtm, f, dtm)));
        f = __builtin_fmaf(DT, s, f);
        s = s2;
    }

    // ---------------- scan2: scalar weights av^(25*2^j) ----------------
    sA[tid] = Rv; sB[tid] = Rq;
    __syncthreads();
#pragma unroll
    for (int j = 0; j < LEVELS; ++j) {
        const int off = 1 << j;
        float nv = 0.0f, nq = 0.0f;
        const bool has = (cc >= off);
        if (has) { nv = sA[tid - off * LANES]; nq = sB[tid - off * LANES]; }
        __syncthreads();
        if (has) {
            Rv = __builtin_fmaf(AVP[j], nv, Rv);
            Rq = __builtin_fmaf(AVP[j], nq, Rq);
            sA[tid] = Rv; sB[tid] = Rq;
        }
        __syncthreads();
    }
    float v = avc, q = avc;                 // v0 = q0 = 1
    if (cc > 0) { v += sA[tid - LANES]; q += sB[tid - LANES]; }

    // ---------------- P3: consume stashed f, compute y, NT store ----------------
    // f values are the exact bits P2 produced (same thread wrote the slot),
    // so numerics are identical to a replay.
    float* op = out + cc * (CL * BATCH) + sim;
#pragma unroll 5
    for (int j = 0; j < CL; ++j) {
        const float fj   = zt[zbase + j * GSIMS];
        const float invf = __builtin_amdgcn_rcpf(fj);
        const float e2   = EXP2F(lc * invf);
        const float t1   = __builtin_fmaf(-fj, e2, fj);
        const float vn   = __builtin_fmaf(av, v, dt_il * fj);
        const float qn   = __builtin_fmaf(av, q, kq * t1);
        const float invv = __builtin_amdgcn_rcpf(vn);
        const float y = __builtin_fmaf(-c2, qn * invv,
                        __builtin_fmaf(-c3, vn,
                        __builtin_fmaf(-c1, qn, c0)));
        __builtin_nontemporal_store(y, op + j * BATCH);
        v = vn; q = qn;
    }
}

extern "C" void kernel_launch(void* const* d_in, const int* in_sizes, int n_in,
                              void* d_out, int out_size, void* d_ws, size_t ws_size,
                              hipStream_t stream) {
    const float* noise   = (const float*)d_in[0];
    const float* p_sigma = (const float*)d_in[1];
    const float* p_mu    = (const float*)d_in[2];
    const float* p_lamb  = (const float*)d_in[3];
    const float* p_beta  = (const float*)d_in[4];
    const float* p_psi   = (const float*)d_in[5];
    const float* p_phi   = (const float*)d_in[6];
    const float* p_chi   = (const float*)d_in[7];

    balloon_scan<<<BATCH / GSIMS, NTHREADS, 0, stream>>>(
        noise, p_sigma, p_mu, p_lamb, p_beta, p_psi, p_phi, p_chi,
        (float*)d_out);
}